// Round 4
// baseline (19454.710 us; speedup 1.0000x reference)
//
#include <hip/hip_runtime.h>
#include <math.h>

#define HD 128
#define TR 32        // rows per GEMM tile
#define NCHUNK 4     // dst-range chunks for pooled accumulation

static __device__ __forceinline__ unsigned short f2bf(float f) {
    unsigned int u = __float_as_uint(f);
    u += 0x7fffu + ((u >> 16) & 1u);
    return (unsigned short)(u >> 16);
}
static __device__ __forceinline__ float bf2f(unsigned short s) {
    return __uint_as_float(((unsigned int)s) << 16);
}

// ---------------------------------------------------------------- diagnostic
__global__ void k_diag(float* __restrict__ out, int n, float val) {
    for (int i = blockIdx.x * blockDim.x + threadIdx.x; i < n; i += gridDim.x * blockDim.x)
        out[i] = val;
}

// ---------------------------------------------------------------- utility
__global__ void k_zero(float* __restrict__ p, int n) {
    for (int i = threadIdx.x; i < n; i += blockDim.x) p[i] = 0.f;
}

// ---------------------------------------------------------------- layer 0
__global__ void k_init_p0(const float* __restrict__ vf, const float* __restrict__ eps,
                          float* __restrict__ p0, int n) {
    float ep = 1.f + eps[0];
    for (int i = blockIdx.x * blockDim.x + threadIdx.x; i < n; i += gridDim.x * blockDim.x)
        p0[i] = ep * vf[i];
}

__global__ void k_scatter0(const float* __restrict__ vf, const int* __restrict__ src,
                           const int* __restrict__ dst, float* __restrict__ p0, int e) {
    for (int i = blockIdx.x * blockDim.x + threadIdx.x; i < e; i += gridDim.x * blockDim.x)
        unsafeAtomicAdd(&p0[dst[i]], vf[src[i]]);
}

__global__ void k_p0_stats(const float* __restrict__ p0, float* __restrict__ stats, int n) {
    __shared__ float rs[256], rq[256];
    float s = 0.f, q = 0.f;
    for (int i = blockIdx.x * blockDim.x + threadIdx.x; i < n; i += gridDim.x * blockDim.x) {
        float v = p0[i]; s += v; q += v * v;
    }
    int t = threadIdx.x;
    rs[t] = s; rq[t] = q;
    __syncthreads();
    for (int o = 128; o > 0; o >>= 1) {
        if (t < o) { rs[t] += rs[t + o]; rq[t] += rq[t + o]; }
        __syncthreads();
    }
    if (t == 0) { unsafeAtomicAdd(&stats[0], rs[0]); unsafeAtomicAdd(&stats[1], rq[0]); }
}

// layer-0 inner BN as per-channel affine of (p - mp):
//   x[i][c] = relu((p[i]-mp) * A0[c] + Sh0[c]),  A0[c] = W1c * rsqrt(varp*W1c^2+1e-5) * g1c
__global__ void k_l0_prep(float* __restrict__ stats, const float* __restrict__ W1,
                          const float* __restrict__ g1, const float* __restrict__ bb1,
                          float* __restrict__ A0, float* __restrict__ Sh0, int n) {
    float mp = stats[0] / n;
    float vp = stats[1] / n - mp * mp;
    int c = threadIdx.x;
    float w = W1[c];
    A0[c] = w * rsqrtf(vp * w * w + 1e-5f) * g1[c];
    Sh0[c] = bb1[c];
    if (c == 0) stats[2] = mp;
}

// ---------------------------------------------------------------- GEMM (n x 128) @ (128 x 128) + stats
// MODE 0: A = in_f32 (raw, chunk accumulator C)
// MODE 1: A = relu(bf16(in)*tsc[k]+tsh[k])   (full-N, z1 in bf16)
// MODE 2: A = relu((p0[r]-mp)*tsc[k]+tsh[k]) (p0 scalar per row)
// out(bf16) = A@W + bias; accumulates per-channel sum/sumsq (f32) into gsum/gsq.
template <int MODE>
__global__ __launch_bounds__(256) void k_gemm(
    const void* __restrict__ in_, const float* __restrict__ W,
    const float* __restrict__ bias,
    const float* __restrict__ tsc, const float* __restrict__ tsh,
    const float* __restrict__ mstat,
    unsigned short* __restrict__ out,
    float* __restrict__ gsum, float* __restrict__ gsq, int n) {
    __shared__ float Wl[HD * HD];  // 64 KB
    const int t  = threadIdx.x;
    const int cg = t & 31;   // 32 channel groups of 4
    const int rg = t >> 5;   // 8 row groups of 4
    const int c0 = cg * 4;

    const float* inf          = (const float*)in_;
    const unsigned short* inb = (const unsigned short*)in_;

    for (int i = t; i < HD * HD; i += 256)  // scalar: input ptr alignment unknown
        Wl[i] = W[i];
    __syncthreads();

    float mp = 0.f;
    if (MODE == 2) mp = mstat[2];
    const float bvx = bias[c0], bvy = bias[c0 + 1], bvz = bias[c0 + 2], bvw = bias[c0 + 3];

    float s[4] = {0, 0, 0, 0}, q[4] = {0, 0, 0, 0};
    const int ntiles = n / TR;
    for (int tile = blockIdx.x; tile < ntiles; tile += gridDim.x) {
        const int rbase = tile * TR + rg * 4;
        float acc[4][4];
#pragma unroll
        for (int a = 0; a < 4; a++)
#pragma unroll
            for (int b = 0; b < 4; b++) acc[a][b] = 0.f;

        float pr[4];
        if (MODE == 2) {
#pragma unroll
            for (int rr = 0; rr < 4; rr++) pr[rr] = inf[rbase + rr] - mp;
        }

        for (int k = 0; k < HD; k += 4) {
            float xk[4][4];
            if (MODE == 2) {
                float4 a4 = *(const float4*)&tsc[k];   // ws pointers: aligned
                float4 b4 = *(const float4*)&tsh[k];
#pragma unroll
                for (int rr = 0; rr < 4; rr++) {
                    xk[rr][0] = fmaxf(pr[rr] * a4.x + b4.x, 0.f);
                    xk[rr][1] = fmaxf(pr[rr] * a4.y + b4.y, 0.f);
                    xk[rr][2] = fmaxf(pr[rr] * a4.z + b4.z, 0.f);
                    xk[rr][3] = fmaxf(pr[rr] * a4.w + b4.w, 0.f);
                }
            } else if (MODE == 1) {
                float4 sc4 = *(const float4*)&tsc[k];
                float4 sh4 = *(const float4*)&tsh[k];
#pragma unroll
                for (int rr = 0; rr < 4; rr++) {
                    uint2 u = *(const uint2*)&inb[(size_t)(rbase + rr) * HD + k];
                    float vx = bf2f((unsigned short)(u.x & 0xffffu));
                    float vy = bf2f((unsigned short)(u.x >> 16));
                    float vz = bf2f((unsigned short)(u.y & 0xffffu));
                    float vw = bf2f((unsigned short)(u.y >> 16));
                    xk[rr][0] = fmaxf(vx * sc4.x + sh4.x, 0.f);
                    xk[rr][1] = fmaxf(vy * sc4.y + sh4.y, 0.f);
                    xk[rr][2] = fmaxf(vz * sc4.z + sh4.z, 0.f);
                    xk[rr][3] = fmaxf(vw * sc4.w + sh4.w, 0.f);
                }
            } else {
#pragma unroll
                for (int rr = 0; rr < 4; rr++) {
                    float4 av = *(const float4*)&inf[(size_t)(rbase + rr) * HD + k];
                    xk[rr][0] = av.x; xk[rr][1] = av.y; xk[rr][2] = av.z; xk[rr][3] = av.w;
                }
            }
#pragma unroll
            for (int kk = 0; kk < 4; kk++) {
                float4 wv = *(const float4*)&Wl[(k + kk) * HD + c0];
#pragma unroll
                for (int rr = 0; rr < 4; rr++) {
                    acc[rr][0] += xk[rr][kk] * wv.x;
                    acc[rr][1] += xk[rr][kk] * wv.y;
                    acc[rr][2] += xk[rr][kk] * wv.z;
                    acc[rr][3] += xk[rr][kk] * wv.w;
                }
            }
        }
#pragma unroll
        for (int rr = 0; rr < 4; rr++) {
            float ox = acc[rr][0] + bvx;
            float oy = acc[rr][1] + bvy;
            float oz = acc[rr][2] + bvz;
            float ow = acc[rr][3] + bvw;
            unsigned int lo = (unsigned int)f2bf(ox) | ((unsigned int)f2bf(oy) << 16);
            unsigned int hi = (unsigned int)f2bf(oz) | ((unsigned int)f2bf(ow) << 16);
            *(uint2*)&out[(size_t)(rbase + rr) * HD + c0] = make_uint2(lo, hi);
            s[0] += ox; s[1] += oy; s[2] += oz; s[3] += ow;
            q[0] += ox * ox; q[1] += oy * oy; q[2] += oz * oz; q[3] += ow * ow;
        }
    }

    // per-block stats reduction (reuse Wl as scratch)
    __syncthreads();
    float* red = Wl;
#pragma unroll
    for (int cc = 0; cc < 4; cc++) {
        red[rg * HD + c0 + cc] = s[cc];
        red[8 * HD + rg * HD + c0 + cc] = q[cc];
    }
    __syncthreads();
    if (t < HD) {
        float ts = 0.f, tq = 0.f;
#pragma unroll
        for (int g2 = 0; g2 < 8; g2++) {
            ts += red[g2 * HD + t];
            tq += red[8 * HD + g2 * HD + t];
        }
        unsafeAtomicAdd(&gsum[t], ts);
        unsafeAtomicAdd(&gsq[t], tq);
    }
}

// mean/var -> affine (sc, sh): bn(z) = z*sc + sh
__global__ void k_finalize(const float* __restrict__ gsum, const float* __restrict__ gsq,
                           const float* __restrict__ g, const float* __restrict__ b,
                           float* __restrict__ sc, float* __restrict__ sh, int n) {
    int c = threadIdx.x;
    float m = gsum[c] / n;
    float v = gsq[c] / n - m * m;
    float s = rsqrtf(v + 1e-5f) * g[c];
    sc[c] = s;
    sh[c] = b[c] - m * s;
}

// in-place on bf16 H: h = relu(z*sc+sh)
__global__ void k_prep_ip(unsigned short* __restrict__ hz, const float* __restrict__ sc,
                          const float* __restrict__ sh, int n4) {
    for (int i = blockIdx.x * blockDim.x + threadIdx.x; i < n4; i += gridDim.x * blockDim.x) {
        int c0 = (i & 31) * 4;
        uint2 u = *(const uint2*)&hz[(size_t)i * 4];
        float4 s4 = *(const float4*)&sc[c0];
        float4 h4 = *(const float4*)&sh[c0];
        float vx = fmaxf(bf2f((unsigned short)(u.x & 0xffffu)) * s4.x + h4.x, 0.f);
        float vy = fmaxf(bf2f((unsigned short)(u.x >> 16)) * s4.y + h4.y, 0.f);
        float vz = fmaxf(bf2f((unsigned short)(u.y & 0xffffu)) * s4.z + h4.z, 0.f);
        float vw = fmaxf(bf2f((unsigned short)(u.y >> 16)) * s4.w + h4.w, 0.f);
        unsigned int lo = (unsigned int)f2bf(vx) | ((unsigned int)f2bf(vy) << 16);
        unsigned int hi = (unsigned int)f2bf(vz) | ((unsigned int)f2bf(vw) << 16);
        *(uint2*)&hz[(size_t)i * 4] = make_uint2(lo, hi);
    }
}

// C[r][:] = (1+eps)*h[base+r][:]   (chunk pooled init, bf16 -> f32)
__global__ void k_pool_init(const unsigned short* __restrict__ h, const float* __restrict__ eps,
                            int li, float* __restrict__ C, int base, int n4) {
    float ep = 1.f + eps[li];
    for (int i = blockIdx.x * blockDim.x + threadIdx.x; i < n4; i += gridDim.x * blockDim.x) {
        uint2 u = *(const uint2*)&h[(size_t)base * HD + (size_t)i * 4];
        float4 v;
        v.x = bf2f((unsigned short)(u.x & 0xffffu)) * ep;
        v.y = bf2f((unsigned short)(u.x >> 16)) * ep;
        v.z = bf2f((unsigned short)(u.y & 0xffffu)) * ep;
        v.w = bf2f((unsigned short)(u.y >> 16)) * ep;
        *(float4*)&C[(size_t)i * 4] = v;
    }
}

// C[dst-base] += h[src] for edges with dst in [base, base+nc) — one wave/edge
__global__ void k_scatter_chunk(const unsigned short* __restrict__ h,
                                const int* __restrict__ src, const int* __restrict__ dst,
                                float* __restrict__ C, int e, int base, int nc) {
    int gid  = blockIdx.x * blockDim.x + threadIdx.x;
    int lane = threadIdx.x & 63;
    int w    = gid >> 6;
    int nw   = (gridDim.x * blockDim.x) >> 6;
    for (int i = w; i < e; i += nw) {
        int d = dst[i];
        unsigned int rel = (unsigned int)(d - base);
        if (rel < (unsigned int)nc) {
            int s2 = src[i];
            unsigned int v = *(const unsigned int*)&h[(size_t)s2 * HD + lane * 2];
            float* p = &C[(size_t)rel * HD + lane * 2];
            unsafeAtomicAdd(p, bf2f((unsigned short)(v & 0xffffu)));
            unsafeAtomicAdd(p + 1, bf2f((unsigned short)(v >> 16)));
        }
    }
}

// classifier head: bn+relu on bf16 z, 2-logit fc, softmax — one wave per row
__global__ void k_head(const unsigned short* __restrict__ z, const float* __restrict__ sc,
                       const float* __restrict__ sh, const float* __restrict__ fw,
                       const float* __restrict__ fb, float* __restrict__ out, int n) {
    int gid  = blockIdx.x * blockDim.x + threadIdx.x;
    int lane = threadIdx.x & 63;
    int w    = gid >> 6;
    int nw   = (gridDim.x * blockDim.x) >> 6;
    int c    = lane * 2;
    float s0 = sc[c], s1 = sc[c + 1], t0 = sh[c], t1 = sh[c + 1];
    float w00 = fw[c * 2], w01 = fw[c * 2 + 1], w10 = fw[c * 2 + 2], w11 = fw[c * 2 + 3];
    float fb0 = fb[0], fb1 = fb[1];
    for (int r = w; r < n; r += nw) {
        unsigned int u = *(const unsigned int*)&z[(size_t)r * HD + c];
        float zx = bf2f((unsigned short)(u & 0xffffu));
        float zy = bf2f((unsigned short)(u >> 16));
        float x0 = fmaxf(zx * s0 + t0, 0.f);
        float x1 = fmaxf(zy * s1 + t1, 0.f);
        float l0 = x0 * w00 + x1 * w10;
        float l1 = x0 * w01 + x1 * w11;
#pragma unroll
        for (int o = 32; o > 0; o >>= 1) {
            l0 += __shfl_xor(l0, o, 64);
            l1 += __shfl_xor(l1, o, 64);
        }
        if (lane == 0) {
            l0 += fb0; l1 += fb1;
            float m  = fmaxf(l0, l1);
            float e0 = expf(l0 - m), e1 = expf(l1 - m);
            float inv = 1.f / (e0 + e1);
            *(float2*)&out[(size_t)r * 2] = make_float2(e0 * inv, e1 * inv);
        }
    }
}

extern "C" void kernel_launch(void* const* d_in, const int* in_sizes, int n_in,
                              void* d_out, int out_size, void* d_ws, size_t ws_size,
                              hipStream_t stream) {
    const float* vf    = (const float*)d_in[1];
    const int*   src   = (const int*)d_in[2];
    const int*   dst   = (const int*)d_in[3];
    const float* eps   = (const float*)d_in[4];
    const float* W1_0  = (const float*)d_in[5];
    const float* g1_0  = (const float*)d_in[7];
    const float* bb1_0 = (const float*)d_in[8];
    const float* W2_0  = (const float*)d_in[9];
    const float* b2_0  = (const float*)d_in[10];
    const float* bn0g  = (const float*)d_in[11];
    const float* bn0b  = (const float*)d_in[12];
    const float* W1s   = (const float*)d_in[13];
    const float* b1s   = (const float*)d_in[14];
    const float* g1s   = (const float*)d_in[15];
    const float* bb1s  = (const float*)d_in[16];
    const float* W2s   = (const float*)d_in[17];
    const float* b2s   = (const float*)d_in[18];
    const float* bngs  = (const float*)d_in[19];
    const float* bnbs  = (const float*)d_in[20];
    const float* fw    = (const float*)d_in[21];
    const float* fb    = (const float*)d_in[22];
    float* out = (float*)d_out;

    const int N  = in_sizes[1];  // 400000
    const int E  = in_sizes[2];  // 6400000
    const int NC = N / NCHUNK;   // 100000 rows per chunk (divisible by TR)

    // layout: H(bf16 N*128) | Z(bf16 N*128) | C(f32 NC*128) | p0(f32 N) | small
    const size_t needed = (size_t)N * HD * 2 * 2 + (size_t)NC * HD * 4 + (size_t)N * 4 + 16384;
    if (ws_size < needed) {
        float code = (float)(double)(ws_size >> 20);  // absmax ~= ws MiB
        k_diag<<<2048, 256, 0, stream>>>(out, out_size, code);
        return;
    }

    unsigned short* H = (unsigned short*)d_ws;
    unsigned short* Z = H + (size_t)N * HD;
    float* C          = (float*)(Z + (size_t)N * HD);
    float* p0         = C + (size_t)NC * HD;
    float* stats      = p0 + N;     // [0]=sum(p) [1]=sumsq(p) [2]=mean(p)
    float* gsum       = stats + 8;  // 128
    float* gsq        = gsum + HD;  // 128
    float* sc1        = gsq + HD;
    float* sh1        = sc1 + HD;
    float* sc2        = sh1 + HD;
    float* sh2        = sc2 + HD;
    float* A0         = sh2 + HD;
    float* Sh0        = A0 + HD;

    // -------- layer 0 (scalar features, rank-1 inner BN shortcut)
    k_init_p0<<<1024, 256, 0, stream>>>(vf, eps, p0, N);
    k_zero<<<1, 256, 0, stream>>>(stats, 8);
    k_scatter0<<<4096, 256, 0, stream>>>(vf, src, dst, p0, E);
    k_p0_stats<<<1024, 256, 0, stream>>>(p0, stats, N);
    k_l0_prep<<<1, 128, 0, stream>>>(stats, W1_0, g1_0, bb1_0, A0, Sh0, N);
    k_zero<<<1, 256, 0, stream>>>(gsum, 2 * HD);
    k_gemm<2><<<2048, 256, 0, stream>>>(p0, W2_0, b2_0, A0, Sh0, stats, H, gsum, gsq, N);
    k_finalize<<<1, 128, 0, stream>>>(gsum, gsq, bn0g, bn0b, sc2, sh2, N);

    // -------- layers 1..3
    for (int l = 0; l < 3; l++) {
        // h = relu(z2*sc2+sh2), in-place on H
        k_prep_ip<<<4096, 256, 0, stream>>>(H, sc2, sh2, N * (HD / 4));
        // z1 = (A@h + (1+eps)h) @ W1 + b1, chunked over dst ranges
        k_zero<<<1, 256, 0, stream>>>(gsum, 2 * HD);
        for (int c = 0; c < NCHUNK; c++) {
            int base = c * NC;
            k_pool_init<<<2048, 256, 0, stream>>>(H, eps, l + 1, C, base, NC * (HD / 4));
            k_scatter_chunk<<<8192, 256, 0, stream>>>(H, src, dst, C, E, base, NC);
            k_gemm<0><<<2048, 256, 0, stream>>>(C, W1s + (size_t)l * HD * HD, b1s + l * HD,
                                                nullptr, nullptr, nullptr,
                                                Z + (size_t)base * HD, gsum, gsq, NC);
        }
        k_finalize<<<1, 128, 0, stream>>>(gsum, gsq, g1s + l * HD, bb1s + l * HD, sc1, sh1, N);
        // z2 = relu(z1*sc1+sh1) @ W2 + b2  (full N, bf16 in/out)
        k_zero<<<1, 256, 0, stream>>>(gsum, 2 * HD);
        k_gemm<1><<<2048, 256, 0, stream>>>(Z, W2s + (size_t)l * HD * HD, b2s + l * HD,
                                            sc1, sh1, nullptr, H, gsum, gsq, N);
        k_finalize<<<1, 128, 0, stream>>>(gsum, gsq, bngs + l * HD, bnbs + l * HD, sc2, sh2, N);
    }

    // -------- classifier head + softmax
    k_head<<<4096, 256, 0, stream>>>(H, sc2, sh2, fw, fb, out, N);
}

// Round 5
// 4557.342 us; speedup vs baseline: 4.2689x; 4.2689x over previous
//
#include <hip/hip_runtime.h>
#include <math.h>

#define HD 128
#define TR 32        // rows per GEMM tile

static __device__ __forceinline__ unsigned short f2bf(float f) {
    unsigned int u = __float_as_uint(f);
    u += 0x7fffu + ((u >> 16) & 1u);
    return (unsigned short)(u >> 16);
}
static __device__ __forceinline__ float bf2f(unsigned short s) {
    return __uint_as_float(((unsigned int)s) << 16);
}

// ---------------------------------------------------------------- diagnostic
__global__ void k_diag(float* __restrict__ out, int n, float val) {
    for (int i = blockIdx.x * blockDim.x + threadIdx.x; i < n; i += gridDim.x * blockDim.x)
        out[i] = val;
}

// ---------------------------------------------------------------- utility
__global__ void k_zero(float* __restrict__ p, int n) {
    for (int i = threadIdx.x; i < n; i += blockDim.x) p[i] = 0.f;
}
__global__ void k_zeroi(int* __restrict__ p, int n) {
    for (int i = blockIdx.x * blockDim.x + threadIdx.x; i < n; i += gridDim.x * blockDim.x)
        p[i] = 0;
}
__global__ void k_copyi(const int* __restrict__ a, int* __restrict__ b, int n) {
    for (int i = blockIdx.x * blockDim.x + threadIdx.x; i < n; i += gridDim.x * blockDim.x)
        b[i] = a[i];
}

// ---------------------------------------------------------------- CSR build
// counts at row_ptr[d+1]; row_ptr[0]=0; inclusive scan over the whole array
// then yields row starts.
__global__ void k_hist(const int* __restrict__ dst, int* __restrict__ row_ptr, int e) {
    for (int i = blockIdx.x * blockDim.x + threadIdx.x; i < e; i += gridDim.x * blockDim.x)
        atomicAdd(&row_ptr[dst[i] + 1], 1);
}

#define SCAN_B 1024
__global__ void k_scan_block(int* __restrict__ a, int n, int* __restrict__ bsum) {
    __shared__ int s[SCAN_B];
    int base = blockIdx.x * SCAN_B;
    int i = base + threadIdx.x;
    int v = (i < n) ? a[i] : 0;
    s[threadIdx.x] = v;
    __syncthreads();
    for (int o = 1; o < SCAN_B; o <<= 1) {
        int t = (threadIdx.x >= o) ? s[threadIdx.x - o] : 0;
        __syncthreads();
        s[threadIdx.x] += t;
        __syncthreads();
    }
    if (i < n) a[i] = s[threadIdx.x];
    if (threadIdx.x == 0) bsum[blockIdx.x] = s[SCAN_B - 1];
}
__global__ void k_scan_serial(int* __restrict__ bsum, int nb) {
    int run = 0;
    for (int b = 0; b < nb; b++) { int t = bsum[b]; bsum[b] = run; run += t; }
}
__global__ void k_scan_add(int* __restrict__ a, int n, const int* __restrict__ bsum) {
    int base = blockIdx.x * SCAN_B;
    int i = base + threadIdx.x;
    if (i < n) a[i] += bsum[blockIdx.x];
}

__global__ void k_bucket(const int* __restrict__ src, const int* __restrict__ dst,
                         int* __restrict__ fill, int* __restrict__ src_sorted, int e) {
    for (int i = blockIdx.x * blockDim.x + threadIdx.x; i < e; i += gridDim.x * blockDim.x) {
        int pos = atomicAdd(&fill[dst[i]], 1);
        src_sorted[pos] = src[i];
    }
}

// ---------------------------------------------------------------- layer 0
// p0[d] = (1+eps)*vf[d] + sum_{nbr} vf[src]   (CSR gather, no atomics)
__global__ void k_pool0(const float* __restrict__ vf, const int* __restrict__ row_ptr,
                        const int* __restrict__ srcs, const float* __restrict__ eps,
                        float* __restrict__ p0, int n) {
    float ep = 1.f + eps[0];
    for (int i = blockIdx.x * blockDim.x + threadIdx.x; i < n; i += gridDim.x * blockDim.x) {
        float s = ep * vf[i];
        int j1 = row_ptr[i + 1];
        for (int j = row_ptr[i]; j < j1; j++) s += vf[srcs[j]];
        p0[i] = s;
    }
}

__global__ void k_p0_stats(const float* __restrict__ p0, float* __restrict__ stats, int n) {
    __shared__ float rs[256], rq[256];
    float s = 0.f, q = 0.f;
    for (int i = blockIdx.x * blockDim.x + threadIdx.x; i < n; i += gridDim.x * blockDim.x) {
        float v = p0[i]; s += v; q += v * v;
    }
    int t = threadIdx.x;
    rs[t] = s; rq[t] = q;
    __syncthreads();
    for (int o = 128; o > 0; o >>= 1) {
        if (t < o) { rs[t] += rs[t + o]; rq[t] += rq[t + o]; }
        __syncthreads();
    }
    if (t == 0) { unsafeAtomicAdd(&stats[0], rs[0]); unsafeAtomicAdd(&stats[1], rq[0]); }
}

// layer-0 inner BN as per-channel affine of (p - mp)
__global__ void k_l0_prep(float* __restrict__ stats, const float* __restrict__ W1,
                          const float* __restrict__ g1, const float* __restrict__ bb1,
                          float* __restrict__ A0, float* __restrict__ Sh0, int n) {
    float mp = stats[0] / n;
    float vp = stats[1] / n - mp * mp;
    int c = threadIdx.x;
    float w = W1[c];
    A0[c] = w * rsqrtf(vp * w * w + 1e-5f) * g1[c];
    Sh0[c] = bb1[c];
    if (c == 0) stats[2] = mp;
}

// ---------------------------------------------------------------- fused pool + GEMM1
// Per 32-row tile: Phase A gathers pooled rows (CSR) into LDS (f32);
// Phase B computes [32x128]@[128x128] + bias -> bf16 out + BN stats.
__global__ __launch_bounds__(256) void k_pgemm(
    const unsigned short* __restrict__ h, const int* __restrict__ row_ptr,
    const int* __restrict__ src_sorted, const float* __restrict__ eps, int li,
    const float* __restrict__ W, const float* __restrict__ bias,
    unsigned short* __restrict__ out,
    float* __restrict__ gsum, float* __restrict__ gsq, int n) {
    __shared__ float Pl[TR * HD];  // 16 KB
    const int t  = threadIdx.x;
    const int cg = t & 31;   // channel group (Phase B) / lane-in-group (Phase A)
    const int rg = t >> 5;   // row group: 8 groups of 4 rows
    const int c0 = cg * 4;

    const float ep = 1.f + eps[li];
    const float bvx = bias[c0], bvy = bias[c0 + 1], bvz = bias[c0 + 2], bvw = bias[c0 + 3];

    float s[4] = {0, 0, 0, 0}, q[4] = {0, 0, 0, 0};
    const int ntiles = n / TR;
    for (int tile = blockIdx.x; tile < ntiles; tile += gridDim.x) {
        const int rbase = tile * TR + rg * 4;
        // ---- Phase A: gather-pool 4 rows per 32-thread group
#pragma unroll
        for (int rr = 0; rr < 4; rr++) {
            const int r = rbase + rr;
            uint2 u = *(const uint2*)&h[(size_t)r * HD + cg * 4];
            float a0 = bf2f((unsigned short)(u.x & 0xffffu)) * ep;
            float a1 = bf2f((unsigned short)(u.x >> 16)) * ep;
            float a2 = bf2f((unsigned short)(u.y & 0xffffu)) * ep;
            float a3 = bf2f((unsigned short)(u.y >> 16)) * ep;
            const int j1 = row_ptr[r + 1];
            for (int j = row_ptr[r]; j < j1; j++) {
                int s2 = src_sorted[j];
                uint2 v = *(const uint2*)&h[(size_t)s2 * HD + cg * 4];
                a0 += bf2f((unsigned short)(v.x & 0xffffu));
                a1 += bf2f((unsigned short)(v.x >> 16));
                a2 += bf2f((unsigned short)(v.y & 0xffffu));
                a3 += bf2f((unsigned short)(v.y >> 16));
            }
            *(float4*)&Pl[(rg * 4 + rr) * HD + cg * 4] = make_float4(a0, a1, a2, a3);
        }
        __syncthreads();
        // ---- Phase B: GEMM from LDS, W streamed from L2
        float acc[4][4];
#pragma unroll
        for (int a = 0; a < 4; a++)
#pragma unroll
            for (int b = 0; b < 4; b++) acc[a][b] = 0.f;

        for (int k = 0; k < HD; k += 4) {
            float4 xr[4];
#pragma unroll
            for (int rr = 0; rr < 4; rr++)
                xr[rr] = *(const float4*)&Pl[(rg * 4 + rr) * HD + k];
#pragma unroll
            for (int kk = 0; kk < 4; kk++) {
                float4 wv = *(const float4*)&W[(size_t)(k + kk) * HD + c0];
#pragma unroll
                for (int rr = 0; rr < 4; rr++) {
                    float xv = (kk == 0) ? xr[rr].x : (kk == 1) ? xr[rr].y
                              : (kk == 2) ? xr[rr].z : xr[rr].w;
                    acc[rr][0] += xv * wv.x;
                    acc[rr][1] += xv * wv.y;
                    acc[rr][2] += xv * wv.z;
                    acc[rr][3] += xv * wv.w;
                }
            }
        }
#pragma unroll
        for (int rr = 0; rr < 4; rr++) {
            float ox = acc[rr][0] + bvx;
            float oy = acc[rr][1] + bvy;
            float oz = acc[rr][2] + bvz;
            float ow = acc[rr][3] + bvw;
            unsigned int lo = (unsigned int)f2bf(ox) | ((unsigned int)f2bf(oy) << 16);
            unsigned int hi = (unsigned int)f2bf(oz) | ((unsigned int)f2bf(ow) << 16);
            *(uint2*)&out[(size_t)(rbase + rr) * HD + c0] = make_uint2(lo, hi);
            s[0] += ox; s[1] += oy; s[2] += oz; s[3] += ow;
            q[0] += ox * ox; q[1] += oy * oy; q[2] += oz * oz; q[3] += ow * ow;
        }
        __syncthreads();  // Pl reused next tile
    }

    // stats reduction (reuse Pl)
    __syncthreads();
    float* red = Pl;
#pragma unroll
    for (int cc = 0; cc < 4; cc++) {
        red[rg * HD + c0 + cc] = s[cc];
        red[8 * HD + rg * HD + c0 + cc] = q[cc];
    }
    __syncthreads();
    if (t < HD) {
        float ts = 0.f, tq = 0.f;
#pragma unroll
        for (int g2 = 0; g2 < 8; g2++) {
            ts += red[g2 * HD + t];
            tq += red[8 * HD + g2 * HD + t];
        }
        unsafeAtomicAdd(&gsum[t], ts);
        unsafeAtomicAdd(&gsq[t], tq);
    }
}

// ---------------------------------------------------------------- GEMM (n x 128) @ (128 x 128) + stats
// MODE 1: A = relu(bf16(in)*tsc[k]+tsh[k])   (full-N, z1 in bf16)
// MODE 2: A = relu((p0[r]-mp)*tsc[k]+tsh[k]) (p0 scalar per row)
template <int MODE>
__global__ __launch_bounds__(256) void k_gemm(
    const void* __restrict__ in_, const float* __restrict__ W,
    const float* __restrict__ bias,
    const float* __restrict__ tsc, const float* __restrict__ tsh,
    const float* __restrict__ mstat,
    unsigned short* __restrict__ out,
    float* __restrict__ gsum, float* __restrict__ gsq, int n) {
    __shared__ float Wl[HD * HD];  // 64 KB
    const int t  = threadIdx.x;
    const int cg = t & 31;
    const int rg = t >> 5;
    const int c0 = cg * 4;

    const float* inf          = (const float*)in_;
    const unsigned short* inb = (const unsigned short*)in_;

    for (int i = t; i < HD * HD; i += 256) Wl[i] = W[i];
    __syncthreads();

    float mp = 0.f;
    if (MODE == 2) mp = mstat[2];
    const float bvx = bias[c0], bvy = bias[c0 + 1], bvz = bias[c0 + 2], bvw = bias[c0 + 3];

    float s[4] = {0, 0, 0, 0}, q[4] = {0, 0, 0, 0};
    const int ntiles = n / TR;
    for (int tile = blockIdx.x; tile < ntiles; tile += gridDim.x) {
        const int rbase = tile * TR + rg * 4;
        float acc[4][4];
#pragma unroll
        for (int a = 0; a < 4; a++)
#pragma unroll
            for (int b = 0; b < 4; b++) acc[a][b] = 0.f;

        float pr[4];
        if (MODE == 2) {
#pragma unroll
            for (int rr = 0; rr < 4; rr++) pr[rr] = inf[rbase + rr] - mp;
        }

        for (int k = 0; k < HD; k += 4) {
            float xk[4][4];
            if (MODE == 2) {
                float4 a4 = *(const float4*)&tsc[k];
                float4 b4 = *(const float4*)&tsh[k];
#pragma unroll
                for (int rr = 0; rr < 4; rr++) {
                    xk[rr][0] = fmaxf(pr[rr] * a4.x + b4.x, 0.f);
                    xk[rr][1] = fmaxf(pr[rr] * a4.y + b4.y, 0.f);
                    xk[rr][2] = fmaxf(pr[rr] * a4.z + b4.z, 0.f);
                    xk[rr][3] = fmaxf(pr[rr] * a4.w + b4.w, 0.f);
                }
            } else {
                float4 sc4 = *(const float4*)&tsc[k];
                float4 sh4 = *(const float4*)&tsh[k];
#pragma unroll
                for (int rr = 0; rr < 4; rr++) {
                    uint2 u = *(const uint2*)&inb[(size_t)(rbase + rr) * HD + k];
                    float vx = bf2f((unsigned short)(u.x & 0xffffu));
                    float vy = bf2f((unsigned short)(u.x >> 16));
                    float vz = bf2f((unsigned short)(u.y & 0xffffu));
                    float vw = bf2f((unsigned short)(u.y >> 16));
                    xk[rr][0] = fmaxf(vx * sc4.x + sh4.x, 0.f);
                    xk[rr][1] = fmaxf(vy * sc4.y + sh4.y, 0.f);
                    xk[rr][2] = fmaxf(vz * sc4.z + sh4.z, 0.f);
                    xk[rr][3] = fmaxf(vw * sc4.w + sh4.w, 0.f);
                }
            }
#pragma unroll
            for (int kk = 0; kk < 4; kk++) {
                float4 wv = *(const float4*)&Wl[(k + kk) * HD + c0];
#pragma unroll
                for (int rr = 0; rr < 4; rr++) {
                    acc[rr][0] += xk[rr][kk] * wv.x;
                    acc[rr][1] += xk[rr][kk] * wv.y;
                    acc[rr][2] += xk[rr][kk] * wv.z;
                    acc[rr][3] += xk[rr][kk] * wv.w;
                }
            }
        }
#pragma unroll
        for (int rr = 0; rr < 4; rr++) {
            float ox = acc[rr][0] + bvx;
            float oy = acc[rr][1] + bvy;
            float oz = acc[rr][2] + bvz;
            float ow = acc[rr][3] + bvw;
            unsigned int lo = (unsigned int)f2bf(ox) | ((unsigned int)f2bf(oy) << 16);
            unsigned int hi = (unsigned int)f2bf(oz) | ((unsigned int)f2bf(ow) << 16);
            *(uint2*)&out[(size_t)(rbase + rr) * HD + c0] = make_uint2(lo, hi);
            s[0] += ox; s[1] += oy; s[2] += oz; s[3] += ow;
            q[0] += ox * ox; q[1] += oy * oy; q[2] += oz * oz; q[3] += ow * ow;
        }
    }

    __syncthreads();
    float* red = Wl;
#pragma unroll
    for (int cc = 0; cc < 4; cc++) {
        red[rg * HD + c0 + cc] = s[cc];
        red[8 * HD + rg * HD + c0 + cc] = q[cc];
    }
    __syncthreads();
    if (t < HD) {
        float ts = 0.f, tq = 0.f;
#pragma unroll
        for (int g2 = 0; g2 < 8; g2++) {
            ts += red[g2 * HD + t];
            tq += red[8 * HD + g2 * HD + t];
        }
        unsafeAtomicAdd(&gsum[t], ts);
        unsafeAtomicAdd(&gsq[t], tq);
    }
}

// mean/var -> affine (sc, sh): bn(z) = z*sc + sh
__global__ void k_finalize(const float* __restrict__ gsum, const float* __restrict__ gsq,
                           const float* __restrict__ g, const float* __restrict__ b,
                           float* __restrict__ sc, float* __restrict__ sh, int n) {
    int c = threadIdx.x;
    float m = gsum[c] / n;
    float v = gsq[c] / n - m * m;
    float s = rsqrtf(v + 1e-5f) * g[c];
    sc[c] = s;
    sh[c] = b[c] - m * s;
}

// in-place on bf16 H: h = relu(z*sc+sh)
__global__ void k_prep_ip(unsigned short* __restrict__ hz, const float* __restrict__ sc,
                          const float* __restrict__ sh, int n4) {
    for (int i = blockIdx.x * blockDim.x + threadIdx.x; i < n4; i += gridDim.x * blockDim.x) {
        int c0 = (i & 31) * 4;
        uint2 u = *(const uint2*)&hz[(size_t)i * 4];
        float4 s4 = *(const float4*)&sc[c0];
        float4 h4 = *(const float4*)&sh[c0];
        float vx = fmaxf(bf2f((unsigned short)(u.x & 0xffffu)) * s4.x + h4.x, 0.f);
        float vy = fmaxf(bf2f((unsigned short)(u.x >> 16)) * s4.y + h4.y, 0.f);
        float vz = fmaxf(bf2f((unsigned short)(u.y & 0xffffu)) * s4.z + h4.z, 0.f);
        float vw = fmaxf(bf2f((unsigned short)(u.y >> 16)) * s4.w + h4.w, 0.f);
        unsigned int lo = (unsigned int)f2bf(vx) | ((unsigned int)f2bf(vy) << 16);
        unsigned int hi = (unsigned int)f2bf(vz) | ((unsigned int)f2bf(vw) << 16);
        *(uint2*)&hz[(size_t)i * 4] = make_uint2(lo, hi);
    }
}

// classifier head
__global__ void k_head(const unsigned short* __restrict__ z, const float* __restrict__ sc,
                       const float* __restrict__ sh, const float* __restrict__ fw,
                       const float* __restrict__ fb, float* __restrict__ out, int n) {
    int gid  = blockIdx.x * blockDim.x + threadIdx.x;
    int lane = threadIdx.x & 63;
    int w    = gid >> 6;
    int nw   = (gridDim.x * blockDim.x) >> 6;
    int c    = lane * 2;
    float s0 = sc[c], s1 = sc[c + 1], t0 = sh[c], t1 = sh[c + 1];
    float w00 = fw[c * 2], w01 = fw[c * 2 + 1], w10 = fw[c * 2 + 2], w11 = fw[c * 2 + 3];
    float fb0 = fb[0], fb1 = fb[1];
    for (int r = w; r < n; r += nw) {
        unsigned int u = *(const unsigned int*)&z[(size_t)r * HD + c];
        float zx = bf2f((unsigned short)(u & 0xffffu));
        float zy = bf2f((unsigned short)(u >> 16));
        float x0 = fmaxf(zx * s0 + t0, 0.f);
        float x1 = fmaxf(zy * s1 + t1, 0.f);
        float l0 = x0 * w00 + x1 * w10;
        float l1 = x0 * w01 + x1 * w11;
#pragma unroll
        for (int o = 32; o > 0; o >>= 1) {
            l0 += __shfl_xor(l0, o, 64);
            l1 += __shfl_xor(l1, o, 64);
        }
        if (lane == 0) {
            l0 += fb0; l1 += fb1;
            float m  = fmaxf(l0, l1);
            float e0 = expf(l0 - m), e1 = expf(l1 - m);
            float inv = 1.f / (e0 + e1);
            *(float2*)&out[(size_t)r * 2] = make_float2(e0 * inv, e1 * inv);
        }
    }
}

extern "C" void kernel_launch(void* const* d_in, const int* in_sizes, int n_in,
                              void* d_out, int out_size, void* d_ws, size_t ws_size,
                              hipStream_t stream) {
    const float* vf    = (const float*)d_in[1];
    const int*   src   = (const int*)d_in[2];
    const int*   dst   = (const int*)d_in[3];
    const float* eps   = (const float*)d_in[4];
    const float* W1_0  = (const float*)d_in[5];
    const float* g1_0  = (const float*)d_in[7];
    const float* bb1_0 = (const float*)d_in[8];
    const float* W2_0  = (const float*)d_in[9];
    const float* b2_0  = (const float*)d_in[10];
    const float* bn0g  = (const float*)d_in[11];
    const float* bn0b  = (const float*)d_in[12];
    const float* W1s   = (const float*)d_in[13];
    const float* b1s   = (const float*)d_in[14];
    const float* g1s   = (const float*)d_in[15];
    const float* bb1s  = (const float*)d_in[16];
    const float* W2s   = (const float*)d_in[17];
    const float* b2s   = (const float*)d_in[18];
    const float* bngs  = (const float*)d_in[19];
    const float* bnbs  = (const float*)d_in[20];
    const float* fw    = (const float*)d_in[21];
    const float* fb    = (const float*)d_in[22];
    float* out = (float*)d_out;

    const int N = in_sizes[1];  // 400000
    const int E = in_sizes[2];  // 6400000

    // layout: H(bf16) | Z(bf16) | p0(f32 N) | stats/vecs | bsum | row_ptr | fill | src_sorted
    const size_t needed = (size_t)N * HD * 2 * 2 + (size_t)(N + 8 + 9 * 128 + 512) * 4
                        + (size_t)(2 * N + 1 + E) * 4;
    if (ws_size < needed) {
        float code = (float)(double)(ws_size >> 20);
        k_diag<<<2048, 256, 0, stream>>>(out, out_size, code);
        return;
    }

    unsigned short* H = (unsigned short*)d_ws;
    unsigned short* Z = H + (size_t)N * HD;
    float* p0         = (float*)(Z + (size_t)N * HD);
    float* stats      = p0 + N;     // [0]=sum(p) [1]=sumsq(p) [2]=mean(p)
    float* gsum       = stats + 8;
    float* gsq        = gsum + HD;
    float* sc1        = gsq + HD;
    float* sh1        = sc1 + HD;
    float* sc2        = sh1 + HD;
    float* sh2        = sc2 + HD;
    float* A0         = sh2 + HD;
    float* Sh0        = A0 + HD;
    int* bsum         = (int*)(Sh0 + HD);     // 512
    int* row_ptr      = bsum + 512;           // N+1
    int* fill         = row_ptr + (N + 1);    // N
    int* src_sorted   = fill + N;             // E

    // -------- CSR build (by dst)
    const int n1 = N + 1;
    const int nsb = (n1 + SCAN_B - 1) / SCAN_B;
    k_zeroi<<<512, 256, 0, stream>>>(row_ptr, n1);
    k_hist<<<4096, 256, 0, stream>>>(dst, row_ptr, E);
    k_scan_block<<<nsb, SCAN_B, 0, stream>>>(row_ptr, n1, bsum);
    k_scan_serial<<<1, 1, 0, stream>>>(bsum, nsb);
    k_scan_add<<<nsb, SCAN_B, 0, stream>>>(row_ptr, n1, bsum);
    k_copyi<<<512, 256, 0, stream>>>(row_ptr, fill, N);
    k_bucket<<<4096, 256, 0, stream>>>(src, dst, fill, src_sorted, E);

    // -------- layer 0 (scalar features, rank-1 inner BN shortcut)
    k_pool0<<<2048, 256, 0, stream>>>(vf, row_ptr, src_sorted, eps, p0, N);
    k_zero<<<1, 256, 0, stream>>>(stats, 8);
    k_p0_stats<<<1024, 256, 0, stream>>>(p0, stats, N);
    k_l0_prep<<<1, 128, 0, stream>>>(stats, W1_0, g1_0, bb1_0, A0, Sh0, N);
    k_zero<<<1, 256, 0, stream>>>(gsum, 2 * HD);
    k_gemm<2><<<2048, 256, 0, stream>>>(p0, W2_0, b2_0, A0, Sh0, stats, H, gsum, gsq, N);
    k_finalize<<<1, 128, 0, stream>>>(gsum, gsq, bn0g, bn0b, sc2, sh2, N);

    // -------- layers 1..3
    for (int l = 0; l < 3; l++) {
        k_prep_ip<<<4096, 256, 0, stream>>>(H, sc2, sh2, N * (HD / 4));
        k_zero<<<1, 256, 0, stream>>>(gsum, 2 * HD);
        k_pgemm<<<2048, 256, 0, stream>>>(H, row_ptr, src_sorted, eps, l + 1,
                                          W1s + (size_t)l * HD * HD, b1s + l * HD,
                                          Z, gsum, gsq, N);
        k_finalize<<<1, 128, 0, stream>>>(gsum, gsq, g1s + l * HD, bb1s + l * HD, sc1, sh1, N);
        k_zero<<<1, 256, 0, stream>>>(gsum, 2 * HD);
        k_gemm<1><<<2048, 256, 0, stream>>>(Z, W2s + (size_t)l * HD * HD, b2s + l * HD,
                                            sc1, sh1, nullptr, H, gsum, gsq, N);
        k_finalize<<<1, 128, 0, stream>>>(gsum, gsq, bngs + l * HD, bnbs + l * HD, sc2, sh2, N);
    }

    // -------- classifier head + softmax
    k_head<<<4096, 256, 0, stream>>>(H, sc2, sh2, fw, fb, out, N);
}

// Round 6
// 3531.100 us; speedup vs baseline: 5.5095x; 1.2906x over previous
//
#include <hip/hip_runtime.h>
#include <math.h>

#define HD 128
#define TR 32        // rows per GEMM tile

static __device__ __forceinline__ unsigned short f2bf(float f) {
    unsigned int u = __float_as_uint(f);
    u += 0x7fffu + ((u >> 16) & 1u);
    return (unsigned short)(u >> 16);
}
static __device__ __forceinline__ float bf2f(unsigned short s) {
    return __uint_as_float(((unsigned int)s) << 16);
}

// accumulate relu(bf16(v)*sc+sh) for 8 channels packed in a uint4
static __device__ __forceinline__ void acc_aff(uint4 v, const float* scv, const float* shv,
                                               float* a) {
    a[0] += fmaxf(bf2f((unsigned short)(v.x & 0xffffu)) * scv[0] + shv[0], 0.f);
    a[1] += fmaxf(bf2f((unsigned short)(v.x >> 16))     * scv[1] + shv[1], 0.f);
    a[2] += fmaxf(bf2f((unsigned short)(v.y & 0xffffu)) * scv[2] + shv[2], 0.f);
    a[3] += fmaxf(bf2f((unsigned short)(v.y >> 16))     * scv[3] + shv[3], 0.f);
    a[4] += fmaxf(bf2f((unsigned short)(v.z & 0xffffu)) * scv[4] + shv[4], 0.f);
    a[5] += fmaxf(bf2f((unsigned short)(v.z >> 16))     * scv[5] + shv[5], 0.f);
    a[6] += fmaxf(bf2f((unsigned short)(v.w & 0xffffu)) * scv[6] + shv[6], 0.f);
    a[7] += fmaxf(bf2f((unsigned short)(v.w >> 16))     * scv[7] + shv[7], 0.f);
}

// ---------------------------------------------------------------- diagnostic
__global__ void k_diag(float* __restrict__ out, int n, float val) {
    for (int i = blockIdx.x * blockDim.x + threadIdx.x; i < n; i += gridDim.x * blockDim.x)
        out[i] = val;
}

// ---------------------------------------------------------------- utility
__global__ void k_zero(float* __restrict__ p, int n) {
    for (int i = threadIdx.x; i < n; i += blockDim.x) p[i] = 0.f;
}
__global__ void k_zeroi(int* __restrict__ p, int n) {
    for (int i = blockIdx.x * blockDim.x + threadIdx.x; i < n; i += gridDim.x * blockDim.x)
        p[i] = 0;
}
__global__ void k_copyi(const int* __restrict__ a, int* __restrict__ b, int n) {
    for (int i = blockIdx.x * blockDim.x + threadIdx.x; i < n; i += gridDim.x * blockDim.x)
        b[i] = a[i];
}

// ---------------------------------------------------------------- CSR build
__global__ void k_hist(const int* __restrict__ dst, int* __restrict__ row_ptr, int e) {
    for (int i = blockIdx.x * blockDim.x + threadIdx.x; i < e; i += gridDim.x * blockDim.x)
        atomicAdd(&row_ptr[dst[i] + 1], 1);
}

#define SCAN_B 1024
__global__ void k_scan_block(int* __restrict__ a, int n, int* __restrict__ bsum) {
    __shared__ int s[SCAN_B];
    int base = blockIdx.x * SCAN_B;
    int i = base + threadIdx.x;
    int v = (i < n) ? a[i] : 0;
    s[threadIdx.x] = v;
    __syncthreads();
    for (int o = 1; o < SCAN_B; o <<= 1) {
        int t = (threadIdx.x >= o) ? s[threadIdx.x - o] : 0;
        __syncthreads();
        s[threadIdx.x] += t;
        __syncthreads();
    }
    if (i < n) a[i] = s[threadIdx.x];
    if (threadIdx.x == 0) bsum[blockIdx.x] = s[SCAN_B - 1];
}
__global__ void k_scan_serial(int* __restrict__ bsum, int nb) {
    int run = 0;
    for (int b = 0; b < nb; b++) { int t = bsum[b]; bsum[b] = run; run += t; }
}
__global__ void k_scan_add(int* __restrict__ a, int n, const int* __restrict__ bsum) {
    int base = blockIdx.x * SCAN_B;
    int i = base + threadIdx.x;
    if (i < n) a[i] += bsum[blockIdx.x];
}

__global__ void k_bucket(const int* __restrict__ src, const int* __restrict__ dst,
                         int* __restrict__ fill, int* __restrict__ src_sorted, int e) {
    for (int i = blockIdx.x * blockDim.x + threadIdx.x; i < e; i += gridDim.x * blockDim.x) {
        int pos = atomicAdd(&fill[dst[i]], 1);
        src_sorted[pos] = src[i];
    }
}

// ---------------------------------------------------------------- layer 0
__global__ void k_pool0(const float* __restrict__ vf, const int* __restrict__ row_ptr,
                        const int* __restrict__ srcs, const float* __restrict__ eps,
                        float* __restrict__ p0, int n) {
    float ep = 1.f + eps[0];
    for (int i = blockIdx.x * blockDim.x + threadIdx.x; i < n; i += gridDim.x * blockDim.x) {
        float s = ep * vf[i];
        int j1 = row_ptr[i + 1];
        for (int j = row_ptr[i]; j < j1; j++) s += vf[srcs[j]];
        p0[i] = s;
    }
}

__global__ void k_p0_stats(const float* __restrict__ p0, float* __restrict__ stats, int n) {
    __shared__ float rs[256], rq[256];
    float s = 0.f, q = 0.f;
    for (int i = blockIdx.x * blockDim.x + threadIdx.x; i < n; i += gridDim.x * blockDim.x) {
        float v = p0[i]; s += v; q += v * v;
    }
    int t = threadIdx.x;
    rs[t] = s; rq[t] = q;
    __syncthreads();
    for (int o = 128; o > 0; o >>= 1) {
        if (t < o) { rs[t] += rs[t + o]; rq[t] += rq[t + o]; }
        __syncthreads();
    }
    if (t == 0) { unsafeAtomicAdd(&stats[0], rs[0]); unsafeAtomicAdd(&stats[1], rq[0]); }
}

__global__ void k_l0_prep(float* __restrict__ stats, const float* __restrict__ W1,
                          const float* __restrict__ g1, const float* __restrict__ bb1,
                          float* __restrict__ A0, float* __restrict__ Sh0, int n) {
    float mp = stats[0] / n;
    float vp = stats[1] / n - mp * mp;
    int c = threadIdx.x;
    float w = W1[c];
    A0[c] = w * rsqrtf(vp * w * w + 1e-5f) * g1[c];
    Sh0[c] = bb1[c];
    if (c == 0) stats[2] = mp;
}

// ---------------------------------------------------------------- fused BN+ReLU+pool+GEMM1
// H holds RAW z2 (pre-BN). Phase A: per dst row, gather sum of
// relu(z*sc+sh) over {self*(1+eps)} ∪ neighbors, 16 lanes/row, uint4 (16B) loads,
// neighbor loop unrolled x4 for memory-level parallelism. Pooled rows -> LDS.
// Phase B: [32x128]@[128x128] + bias -> bf16 out + BN stats.
__global__ __launch_bounds__(256) void k_pgemm(
    const unsigned short* __restrict__ h, const int* __restrict__ row_ptr,
    const int* __restrict__ src_sorted, const float* __restrict__ eps, int li,
    const float* __restrict__ sc, const float* __restrict__ sh,
    const float* __restrict__ W, const float* __restrict__ bias,
    unsigned short* __restrict__ out,
    float* __restrict__ gsum, float* __restrict__ gsq, int n) {
    __shared__ float Pl[TR * HD];  // 16 KB
    const int t = threadIdx.x;
    // Phase A mapping: 16 groups x 16 lanes; lane covers 8 channels (16B)
    const int ga  = t >> 4;
    const int l16 = t & 15;
    const int ca  = l16 * 8;
    // Phase B mapping: 8 row-groups x 32 channel-groups
    const int cg = t & 31;
    const int rg = t >> 5;
    const int c0 = cg * 4;

    const float ep = 1.f + eps[li];
    float scv[8], shv[8];
    *(float4*)&scv[0] = *(const float4*)&sc[ca];
    *(float4*)&scv[4] = *(const float4*)&sc[ca + 4];
    *(float4*)&shv[0] = *(const float4*)&sh[ca];
    *(float4*)&shv[4] = *(const float4*)&sh[ca + 4];
    const float bvx = bias[c0], bvy = bias[c0 + 1], bvz = bias[c0 + 2], bvw = bias[c0 + 3];

    float s[4] = {0, 0, 0, 0}, q[4] = {0, 0, 0, 0};
    const int ntiles = n / TR;
    for (int tile = blockIdx.x; tile < ntiles; tile += gridDim.x) {
        // ---- Phase A: 2 rows per group
#pragma unroll
        for (int rr = 0; rr < 2; rr++) {
            const int r = tile * TR + ga * 2 + rr;
            float a[8];
            {
                uint4 u = *(const uint4*)&h[(size_t)r * HD + ca];
                a[0] = ep * fmaxf(bf2f((unsigned short)(u.x & 0xffffu)) * scv[0] + shv[0], 0.f);
                a[1] = ep * fmaxf(bf2f((unsigned short)(u.x >> 16))     * scv[1] + shv[1], 0.f);
                a[2] = ep * fmaxf(bf2f((unsigned short)(u.y & 0xffffu)) * scv[2] + shv[2], 0.f);
                a[3] = ep * fmaxf(bf2f((unsigned short)(u.y >> 16))     * scv[3] + shv[3], 0.f);
                a[4] = ep * fmaxf(bf2f((unsigned short)(u.z & 0xffffu)) * scv[4] + shv[4], 0.f);
                a[5] = ep * fmaxf(bf2f((unsigned short)(u.z >> 16))     * scv[5] + shv[5], 0.f);
                a[6] = ep * fmaxf(bf2f((unsigned short)(u.w & 0xffffu)) * scv[6] + shv[6], 0.f);
                a[7] = ep * fmaxf(bf2f((unsigned short)(u.w >> 16))     * scv[7] + shv[7], 0.f);
            }
            const int j0 = row_ptr[r], j1 = row_ptr[r + 1];
            int j = j0;
            for (; j + 3 < j1; j += 4) {
                int s0 = src_sorted[j], s1 = src_sorted[j + 1];
                int s2 = src_sorted[j + 2], s3 = src_sorted[j + 3];
                uint4 v0 = *(const uint4*)&h[(size_t)s0 * HD + ca];
                uint4 v1 = *(const uint4*)&h[(size_t)s1 * HD + ca];
                uint4 v2 = *(const uint4*)&h[(size_t)s2 * HD + ca];
                uint4 v3 = *(const uint4*)&h[(size_t)s3 * HD + ca];
                acc_aff(v0, scv, shv, a);
                acc_aff(v1, scv, shv, a);
                acc_aff(v2, scv, shv, a);
                acc_aff(v3, scv, shv, a);
            }
            for (; j < j1; j++) {
                uint4 v = *(const uint4*)&h[(size_t)src_sorted[j] * HD + ca];
                acc_aff(v, scv, shv, a);
            }
            *(float4*)&Pl[(ga * 2 + rr) * HD + ca]     = make_float4(a[0], a[1], a[2], a[3]);
            *(float4*)&Pl[(ga * 2 + rr) * HD + ca + 4] = make_float4(a[4], a[5], a[6], a[7]);
        }
        __syncthreads();
        // ---- Phase B: GEMM from LDS, W streamed from L2
        float acc[4][4];
#pragma unroll
        for (int a2 = 0; a2 < 4; a2++)
#pragma unroll
            for (int b2 = 0; b2 < 4; b2++) acc[a2][b2] = 0.f;

        const int rbase = tile * TR + rg * 4;
        for (int k = 0; k < HD; k += 4) {
            float4 xr[4];
#pragma unroll
            for (int rr = 0; rr < 4; rr++)
                xr[rr] = *(const float4*)&Pl[(rg * 4 + rr) * HD + k];
#pragma unroll
            for (int kk = 0; kk < 4; kk++) {
                float4 wv = *(const float4*)&W[(size_t)(k + kk) * HD + c0];
#pragma unroll
                for (int rr = 0; rr < 4; rr++) {
                    float xv = (kk == 0) ? xr[rr].x : (kk == 1) ? xr[rr].y
                              : (kk == 2) ? xr[rr].z : xr[rr].w;
                    acc[rr][0] += xv * wv.x;
                    acc[rr][1] += xv * wv.y;
                    acc[rr][2] += xv * wv.z;
                    acc[rr][3] += xv * wv.w;
                }
            }
        }
#pragma unroll
        for (int rr = 0; rr < 4; rr++) {
            float ox = acc[rr][0] + bvx;
            float oy = acc[rr][1] + bvy;
            float oz = acc[rr][2] + bvz;
            float ow = acc[rr][3] + bvw;
            unsigned int lo = (unsigned int)f2bf(ox) | ((unsigned int)f2bf(oy) << 16);
            unsigned int hi = (unsigned int)f2bf(oz) | ((unsigned int)f2bf(ow) << 16);
            *(uint2*)&out[(size_t)(rbase + rr) * HD + c0] = make_uint2(lo, hi);
            s[0] += ox; s[1] += oy; s[2] += oz; s[3] += ow;
            q[0] += ox * ox; q[1] += oy * oy; q[2] += oz * oz; q[3] += ow * ow;
        }
        __syncthreads();  // Pl reused next tile
    }

    // stats reduction (reuse Pl)
    __syncthreads();
    float* red = Pl;
#pragma unroll
    for (int cc = 0; cc < 4; cc++) {
        red[rg * HD + c0 + cc] = s[cc];
        red[8 * HD + rg * HD + c0 + cc] = q[cc];
    }
    __syncthreads();
    if (t < HD) {
        float ts = 0.f, tq = 0.f;
#pragma unroll
        for (int g2 = 0; g2 < 8; g2++) {
            ts += red[g2 * HD + t];
            tq += red[8 * HD + g2 * HD + t];
        }
        unsafeAtomicAdd(&gsum[t], ts);
        unsafeAtomicAdd(&gsq[t], tq);
    }
}

// ---------------------------------------------------------------- GEMM (n x 128) @ (128 x 128) + stats
// MODE 1: A = relu(bf16(in)*tsc[k]+tsh[k])
// MODE 2: A = relu((p0[r]-mp)*tsc[k]+tsh[k])   (p0 scalar per row)
template <int MODE>
__global__ __launch_bounds__(256) void k_gemm(
    const void* __restrict__ in_, const float* __restrict__ W,
    const float* __restrict__ bias,
    const float* __restrict__ tsc, const float* __restrict__ tsh,
    const float* __restrict__ mstat,
    unsigned short* __restrict__ out,
    float* __restrict__ gsum, float* __restrict__ gsq, int n) {
    __shared__ float Wl[HD * HD];  // 64 KB
    const int t  = threadIdx.x;
    const int cg = t & 31;
    const int rg = t >> 5;
    const int c0 = cg * 4;

    const float* inf          = (const float*)in_;
    const unsigned short* inb = (const unsigned short*)in_;

    for (int i = t; i < HD * HD; i += 256) Wl[i] = W[i];
    __syncthreads();

    float mp = 0.f;
    if (MODE == 2) mp = mstat[2];
    const float bvx = bias[c0], bvy = bias[c0 + 1], bvz = bias[c0 + 2], bvw = bias[c0 + 3];

    float s[4] = {0, 0, 0, 0}, q[4] = {0, 0, 0, 0};
    const int ntiles = n / TR;
    for (int tile = blockIdx.x; tile < ntiles; tile += gridDim.x) {
        const int rbase = tile * TR + rg * 4;
        float acc[4][4];
#pragma unroll
        for (int a = 0; a < 4; a++)
#pragma unroll
            for (int b = 0; b < 4; b++) acc[a][b] = 0.f;

        float pr[4];
        if (MODE == 2) {
#pragma unroll
            for (int rr = 0; rr < 4; rr++) pr[rr] = inf[rbase + rr] - mp;
        }

        for (int k = 0; k < HD; k += 4) {
            float xk[4][4];
            if (MODE == 2) {
                float4 a4 = *(const float4*)&tsc[k];
                float4 b4 = *(const float4*)&tsh[k];
#pragma unroll
                for (int rr = 0; rr < 4; rr++) {
                    xk[rr][0] = fmaxf(pr[rr] * a4.x + b4.x, 0.f);
                    xk[rr][1] = fmaxf(pr[rr] * a4.y + b4.y, 0.f);
                    xk[rr][2] = fmaxf(pr[rr] * a4.z + b4.z, 0.f);
                    xk[rr][3] = fmaxf(pr[rr] * a4.w + b4.w, 0.f);
                }
            } else {
                float4 sc4 = *(const float4*)&tsc[k];
                float4 sh4 = *(const float4*)&tsh[k];
#pragma unroll
                for (int rr = 0; rr < 4; rr++) {
                    uint2 u = *(const uint2*)&inb[(size_t)(rbase + rr) * HD + k];
                    float vx = bf2f((unsigned short)(u.x & 0xffffu));
                    float vy = bf2f((unsigned short)(u.x >> 16));
                    float vz = bf2f((unsigned short)(u.y & 0xffffu));
                    float vw = bf2f((unsigned short)(u.y >> 16));
                    xk[rr][0] = fmaxf(vx * sc4.x + sh4.x, 0.f);
                    xk[rr][1] = fmaxf(vy * sc4.y + sh4.y, 0.f);
                    xk[rr][2] = fmaxf(vz * sc4.z + sh4.z, 0.f);
                    xk[rr][3] = fmaxf(vw * sc4.w + sh4.w, 0.f);
                }
            }
#pragma unroll
            for (int kk = 0; kk < 4; kk++) {
                float4 wv = *(const float4*)&Wl[(k + kk) * HD + c0];
#pragma unroll
                for (int rr = 0; rr < 4; rr++) {
                    acc[rr][0] += xk[rr][kk] * wv.x;
                    acc[rr][1] += xk[rr][kk] * wv.y;
                    acc[rr][2] += xk[rr][kk] * wv.z;
                    acc[rr][3] += xk[rr][kk] * wv.w;
                }
            }
        }
#pragma unroll
        for (int rr = 0; rr < 4; rr++) {
            float ox = acc[rr][0] + bvx;
            float oy = acc[rr][1] + bvy;
            float oz = acc[rr][2] + bvz;
            float ow = acc[rr][3] + bvw;
            unsigned int lo = (unsigned int)f2bf(ox) | ((unsigned int)f2bf(oy) << 16);
            unsigned int hi = (unsigned int)f2bf(oz) | ((unsigned int)f2bf(ow) << 16);
            *(uint2*)&out[(size_t)(rbase + rr) * HD + c0] = make_uint2(lo, hi);
            s[0] += ox; s[1] += oy; s[2] += oz; s[3] += ow;
            q[0] += ox * ox; q[1] += oy * oy; q[2] += oz * oz; q[3] += ow * ow;
        }
    }

    __syncthreads();
    float* red = Wl;
#pragma unroll
    for (int cc = 0; cc < 4; cc++) {
        red[rg * HD + c0 + cc] = s[cc];
        red[8 * HD + rg * HD + c0 + cc] = q[cc];
    }
    __syncthreads();
    if (t < HD) {
        float ts = 0.f, tq = 0.f;
#pragma unroll
        for (int g2 = 0; g2 < 8; g2++) {
            ts += red[g2 * HD + t];
            tq += red[8 * HD + g2 * HD + t];
        }
        unsafeAtomicAdd(&gsum[t], ts);
        unsafeAtomicAdd(&gsq[t], tq);
    }
}

// mean/var -> affine (sc, sh)
__global__ void k_finalize(const float* __restrict__ gsum, const float* __restrict__ gsq,
                           const float* __restrict__ g, const float* __restrict__ b,
                           float* __restrict__ sc, float* __restrict__ sh, int n) {
    int c = threadIdx.x;
    float m = gsum[c] / n;
    float v = gsq[c] / n - m * m;
    float s = rsqrtf(v + 1e-5f) * g[c];
    sc[c] = s;
    sh[c] = b[c] - m * s;
}

// classifier head (applies final BN affine itself)
__global__ void k_head(const unsigned short* __restrict__ z, const float* __restrict__ sc,
                       const float* __restrict__ sh, const float* __restrict__ fw,
                       const float* __restrict__ fb, float* __restrict__ out, int n) {
    int gid  = blockIdx.x * blockDim.x + threadIdx.x;
    int lane = threadIdx.x & 63;
    int w    = gid >> 6;
    int nw   = (gridDim.x * blockDim.x) >> 6;
    int c    = lane * 2;
    float s0 = sc[c], s1 = sc[c + 1], t0 = sh[c], t1 = sh[c + 1];
    float w00 = fw[c * 2], w01 = fw[c * 2 + 1], w10 = fw[c * 2 + 2], w11 = fw[c * 2 + 3];
    float fb0 = fb[0], fb1 = fb[1];
    for (int r = w; r < n; r += nw) {
        unsigned int u = *(const unsigned int*)&z[(size_t)r * HD + c];
        float zx = bf2f((unsigned short)(u & 0xffffu));
        float zy = bf2f((unsigned short)(u >> 16));
        float x0 = fmaxf(zx * s0 + t0, 0.f);
        float x1 = fmaxf(zy * s1 + t1, 0.f);
        float l0 = x0 * w00 + x1 * w10;
        float l1 = x0 * w01 + x1 * w11;
#pragma unroll
        for (int o = 32; o > 0; o >>= 1) {
            l0 += __shfl_xor(l0, o, 64);
            l1 += __shfl_xor(l1, o, 64);
        }
        if (lane == 0) {
            l0 += fb0; l1 += fb1;
            float m  = fmaxf(l0, l1);
            float e0 = expf(l0 - m), e1 = expf(l1 - m);
            float inv = 1.f / (e0 + e1);
            *(float2*)&out[(size_t)r * 2] = make_float2(e0 * inv, e1 * inv);
        }
    }
}

extern "C" void kernel_launch(void* const* d_in, const int* in_sizes, int n_in,
                              void* d_out, int out_size, void* d_ws, size_t ws_size,
                              hipStream_t stream) {
    const float* vf    = (const float*)d_in[1];
    const int*   src   = (const int*)d_in[2];
    const int*   dst   = (const int*)d_in[3];
    const float* eps   = (const float*)d_in[4];
    const float* W1_0  = (const float*)d_in[5];
    const float* g1_0  = (const float*)d_in[7];
    const float* bb1_0 = (const float*)d_in[8];
    const float* W2_0  = (const float*)d_in[9];
    const float* b2_0  = (const float*)d_in[10];
    const float* bn0g  = (const float*)d_in[11];
    const float* bn0b  = (const float*)d_in[12];
    const float* W1s   = (const float*)d_in[13];
    const float* b1s   = (const float*)d_in[14];
    const float* g1s   = (const float*)d_in[15];
    const float* bb1s  = (const float*)d_in[16];
    const float* W2s   = (const float*)d_in[17];
    const float* b2s   = (const float*)d_in[18];
    const float* bngs  = (const float*)d_in[19];
    const float* bnbs  = (const float*)d_in[20];
    const float* fw    = (const float*)d_in[21];
    const float* fb    = (const float*)d_in[22];
    float* out = (float*)d_out;

    const int N = in_sizes[1];  // 400000
    const int E = in_sizes[2];  // 6400000

    const size_t needed = (size_t)N * HD * 2 * 2 + (size_t)(N + 8 + 9 * 128 + 512) * 4
                        + (size_t)(2 * N + 1 + E) * 4;
    if (ws_size < needed) {
        float code = (float)(double)(ws_size >> 20);
        k_diag<<<2048, 256, 0, stream>>>(out, out_size, code);
        return;
    }

    unsigned short* H = (unsigned short*)d_ws;      // raw z2 (pre-BN), bf16
    unsigned short* Z = H + (size_t)N * HD;         // raw z1 (pre-BN), bf16
    float* p0         = (float*)(Z + (size_t)N * HD);
    float* stats      = p0 + N;
    float* gsum       = stats + 8;
    float* gsq        = gsum + HD;
    float* sc1        = gsq + HD;
    float* sh1        = sc1 + HD;
    float* sc2        = sh1 + HD;
    float* sh2        = sc2 + HD;
    float* A0         = sh2 + HD;
    float* Sh0        = A0 + HD;
    int* bsum         = (int*)(Sh0 + HD);
    int* row_ptr      = bsum + 512;
    int* fill         = row_ptr + (N + 1);
    int* src_sorted   = fill + N;

    // -------- CSR build (by dst)
    const int n1 = N + 1;
    const int nsb = (n1 + SCAN_B - 1) / SCAN_B;
    k_zeroi<<<512, 256, 0, stream>>>(row_ptr, n1);
    k_hist<<<4096, 256, 0, stream>>>(dst, row_ptr, E);
    k_scan_block<<<nsb, SCAN_B, 0, stream>>>(row_ptr, n1, bsum);
    k_scan_serial<<<1, 1, 0, stream>>>(bsum, nsb);
    k_scan_add<<<nsb, SCAN_B, 0, stream>>>(row_ptr, n1, bsum);
    k_copyi<<<512, 256, 0, stream>>>(row_ptr, fill, N);
    k_bucket<<<4096, 256, 0, stream>>>(src, dst, fill, src_sorted, E);

    // -------- layer 0 (scalar features, rank-1 inner BN shortcut)
    k_pool0<<<2048, 256, 0, stream>>>(vf, row_ptr, src_sorted, eps, p0, N);
    k_zero<<<1, 256, 0, stream>>>(stats, 8);
    k_p0_stats<<<1024, 256, 0, stream>>>(p0, stats, N);
    k_l0_prep<<<1, 128, 0, stream>>>(stats, W1_0, g1_0, bb1_0, A0, Sh0, N);
    k_zero<<<1, 256, 0, stream>>>(gsum, 2 * HD);
    k_gemm<2><<<2048, 256, 0, stream>>>(p0, W2_0, b2_0, A0, Sh0, stats, H, gsum, gsq, N);
    k_finalize<<<1, 128, 0, stream>>>(gsum, gsq, bn0g, bn0b, sc2, sh2, N);

    // -------- layers 1..3 (H raw + sc2/sh2 applied on the fly in pgemm)
    for (int l = 0; l < 3; l++) {
        k_zero<<<1, 256, 0, stream>>>(gsum, 2 * HD);
        k_pgemm<<<2048, 256, 0, stream>>>(H, row_ptr, src_sorted, eps, l + 1, sc2, sh2,
                                          W1s + (size_t)l * HD * HD, b1s + l * HD,
                                          Z, gsum, gsq, N);
        k_finalize<<<1, 128, 0, stream>>>(gsum, gsq, g1s + l * HD, bb1s + l * HD, sc1, sh1, N);
        k_zero<<<1, 256, 0, stream>>>(gsum, 2 * HD);
        k_gemm<1><<<2048, 256, 0, stream>>>(Z, W2s + (size_t)l * HD * HD, b2s + l * HD,
                                            sc1, sh1, nullptr, H, gsum, gsq, N);
        k_finalize<<<1, 128, 0, stream>>>(gsum, gsq, bngs + l * HD, bnbs + l * HD, sc2, sh2, N);
    }

    // -------- classifier head + softmax
    k_head<<<4096, 256, 0, stream>>>(H, sc2, sh2, fw, fb, out, N);
}

// Round 7
// 2148.311 us; speedup vs baseline: 9.0558x; 1.6437x over previous
//
#include <hip/hip_runtime.h>
#include <math.h>

#define HD 128
#define LDP 136   // padded LDS row stride in f16 elems (+8 -> bank shift 4/row)

typedef _Float16 f16;
typedef _Float16 f16x8 __attribute__((ext_vector_type(8)));
typedef float f32x4 __attribute__((ext_vector_type(4)));

static __device__ __forceinline__ float h2f(unsigned short s) {
    f16 v; __builtin_memcpy(&v, &s, 2); return (float)v;
}

// ---------------------------------------------------------------- diagnostic
__global__ void k_diag(float* __restrict__ out, int n, float val) {
    for (int i = blockIdx.x * blockDim.x + threadIdx.x; i < n; i += gridDim.x * blockDim.x)
        out[i] = val;
}

// ---------------------------------------------------------------- utility
__global__ void k_zero(float* __restrict__ p, int n) {
    for (int i = threadIdx.x; i < n; i += blockDim.x) p[i] = 0.f;
}
__global__ void k_zeroi(int* __restrict__ p, int n) {
    for (int i = blockIdx.x * blockDim.x + threadIdx.x; i < n; i += gridDim.x * blockDim.x)
        p[i] = 0;
}
__global__ void k_copyi(const int* __restrict__ a, int* __restrict__ b, int n) {
    for (int i = blockIdx.x * blockDim.x + threadIdx.x; i < n; i += gridDim.x * blockDim.x)
        b[i] = a[i];
}

// ---------------------------------------------------------------- CSR build
__global__ void k_hist(const int* __restrict__ dst, int* __restrict__ row_ptr, int e) {
    for (int i = blockIdx.x * blockDim.x + threadIdx.x; i < e; i += gridDim.x * blockDim.x)
        atomicAdd(&row_ptr[dst[i] + 1], 1);
}

#define SCAN_B 1024
__global__ void k_scan_block(int* __restrict__ a, int n, int* __restrict__ bsum) {
    __shared__ int s[SCAN_B];
    int base = blockIdx.x * SCAN_B;
    int i = base + threadIdx.x;
    int v = (i < n) ? a[i] : 0;
    s[threadIdx.x] = v;
    __syncthreads();
    for (int o = 1; o < SCAN_B; o <<= 1) {
        int t = (threadIdx.x >= o) ? s[threadIdx.x - o] : 0;
        __syncthreads();
        s[threadIdx.x] += t;
        __syncthreads();
    }
    if (i < n) a[i] = s[threadIdx.x];
    if (threadIdx.x == 0) bsum[blockIdx.x] = s[SCAN_B - 1];
}
__global__ void k_scan_serial(int* __restrict__ bsum, int nb) {
    int run = 0;
    for (int b = 0; b < nb; b++) { int t = bsum[b]; bsum[b] = run; run += t; }
}
__global__ void k_scan_add(int* __restrict__ a, int n, const int* __restrict__ bsum) {
    int base = blockIdx.x * SCAN_B;
    int i = base + threadIdx.x;
    if (i < n) a[i] += bsum[blockIdx.x];
}
__global__ void k_bucket(const int* __restrict__ src, const int* __restrict__ dst,
                         int* __restrict__ fill, int* __restrict__ src_sorted, int e) {
    for (int i = blockIdx.x * blockDim.x + threadIdx.x; i < e; i += gridDim.x * blockDim.x) {
        int pos = atomicAdd(&fill[dst[i]], 1);
        src_sorted[pos] = src[i];
    }
}

// ---------------------------------------------------------------- layer 0
__global__ void k_pool0(const float* __restrict__ vf, const int* __restrict__ row_ptr,
                        const int* __restrict__ srcs, const float* __restrict__ eps,
                        float* __restrict__ p0, int n) {
    float ep = 1.f + eps[0];
    for (int i = blockIdx.x * blockDim.x + threadIdx.x; i < n; i += gridDim.x * blockDim.x) {
        float s = ep * vf[i];
        int j1 = row_ptr[i + 1];
        for (int j = row_ptr[i]; j < j1; j++) s += vf[srcs[j]];
        p0[i] = s;
    }
}

__global__ void k_p0_stats(const float* __restrict__ p0, float* __restrict__ stats, int n) {
    __shared__ float rs[256], rq[256];
    float s = 0.f, q = 0.f;
    for (int i = blockIdx.x * blockDim.x + threadIdx.x; i < n; i += gridDim.x * blockDim.x) {
        float v = p0[i]; s += v; q += v * v;
    }
    int t = threadIdx.x;
    rs[t] = s; rq[t] = q;
    __syncthreads();
    for (int o = 128; o > 0; o >>= 1) {
        if (t < o) { rs[t] += rs[t + o]; rq[t] += rq[t + o]; }
        __syncthreads();
    }
    if (t == 0) { unsafeAtomicAdd(&stats[0], rs[0]); unsafeAtomicAdd(&stats[1], rq[0]); }
}

__global__ void k_l0_prep(float* __restrict__ stats, const float* __restrict__ W1,
                          const float* __restrict__ g1, const float* __restrict__ bb1,
                          float* __restrict__ A0, float* __restrict__ Sh0, int n) {
    float mp = stats[0] / n;
    float vp = stats[1] / n - mp * mp;
    int c = threadIdx.x;
    float w = W1[c];
    A0[c] = w * rsqrtf(vp * w * w + 1e-5f) * g1[c];
    Sh0[c] = bb1[c];
    if (c == 0) stats[2] = mp;
}

// accumulate relu(f16*sc+sh) for 8 channels
static __device__ __forceinline__ void acc_aff(f16x8 v, const float* scv, const float* shv,
                                               float* a) {
#pragma unroll
    for (int j = 0; j < 8; j++)
        a[j] += fmaxf((float)v[j] * scv[j] + shv[j], 0.f);
}

// ---------------------------------------------------------------- fused BN+ReLU+pool + MFMA GEMM1
// H holds RAW z2 (f16, pre-BN). Phase A: gather pooled rows -> LDS f16.
// Phase B: [32x128]@[128x128] via v_mfma_f32_16x16x32_f16, bias, stats, f16 out.
__global__ __launch_bounds__(256) void k_pgemm(
    const f16* __restrict__ h, const int* __restrict__ row_ptr,
    const int* __restrict__ src_sorted, const float* __restrict__ eps, int li,
    const float* __restrict__ sc, const float* __restrict__ sh,
    const float* __restrict__ W, const float* __restrict__ bias,
    f16* __restrict__ out, float* __restrict__ gsum, float* __restrict__ gsq, int n) {
    __shared__ f16 Wl[HD * LDP];   // W^T [c][k], 34.8 KB
    __shared__ f16 Pl[32 * LDP];   // pooled tile [r][c], 8.7 KB
    const int t = threadIdx.x;
    const int lane = t & 63, w = t >> 6;
    const int l15 = lane & 15, lq = lane >> 4;

    // stage W^T (f32 -> f16, transposed), coalesced reads
    for (int p = 0; p < 64; p++) {
        int idx = p * 256 + t;
        Wl[(idx & 127) * LDP + (idx >> 7)] = (f16)W[idx];
    }

    // Phase A mapping: 16 groups x 16 lanes; lane covers 8 channels
    const int ga = t >> 4, ca = (t & 15) * 8;
    float scv[8], shv[8];
    *(float4*)&scv[0] = *(const float4*)&sc[ca];
    *(float4*)&scv[4] = *(const float4*)&sc[ca + 4];
    *(float4*)&shv[0] = *(const float4*)&sh[ca];
    *(float4*)&shv[4] = *(const float4*)&sh[ca + 4];
    const float ep = 1.f + eps[li];

    // Phase B mapping: wave w -> row-tile (w&1), col-tiles (w>>1)*4 ..+3
    const int rt = (w & 1) * 16;
    const int ctb = (w >> 1) * 4;
    float bv[4];
#pragma unroll
    for (int i = 0; i < 4; i++) bv[i] = bias[(ctb + i) * 16 + l15];

    float s8[8] = {0}, q8[8] = {0};
    const int ntiles = n / 32;
    for (int tile = blockIdx.x; tile < ntiles; tile += gridDim.x) {
        __syncthreads();  // prev epilogue / W staging visible
        // ---- Phase A: 2 rows per 16-lane group
#pragma unroll
        for (int rr = 0; rr < 2; rr++) {
            const int r = tile * 32 + ga * 2 + rr;
            float a[8];
            {
                f16x8 u = *(const f16x8*)&h[(size_t)r * HD + ca];
#pragma unroll
                for (int j = 0; j < 8; j++)
                    a[j] = ep * fmaxf((float)u[j] * scv[j] + shv[j], 0.f);
            }
            const int j0 = row_ptr[r], j1 = row_ptr[r + 1];
            int j = j0;
            for (; j + 3 < j1; j += 4) {
                int s0 = src_sorted[j], s1 = src_sorted[j + 1];
                int s2 = src_sorted[j + 2], s3 = src_sorted[j + 3];
                f16x8 v0 = *(const f16x8*)&h[(size_t)s0 * HD + ca];
                f16x8 v1 = *(const f16x8*)&h[(size_t)s1 * HD + ca];
                f16x8 v2 = *(const f16x8*)&h[(size_t)s2 * HD + ca];
                f16x8 v3 = *(const f16x8*)&h[(size_t)s3 * HD + ca];
                acc_aff(v0, scv, shv, a);
                acc_aff(v1, scv, shv, a);
                acc_aff(v2, scv, shv, a);
                acc_aff(v3, scv, shv, a);
            }
            for (; j < j1; j++) {
                f16x8 v = *(const f16x8*)&h[(size_t)src_sorted[j] * HD + ca];
                acc_aff(v, scv, shv, a);
            }
            f16x8 o;
#pragma unroll
            for (int jj = 0; jj < 8; jj++) o[jj] = (f16)a[jj];
            *(f16x8*)&Pl[(ga * 2 + rr) * LDP + ca] = o;
        }
        __syncthreads();
        // ---- hoist A fragments (rows rt..rt+15)
        f16x8 af[4];
#pragma unroll
        for (int k0 = 0; k0 < 4; k0++)
            af[k0] = *(const f16x8*)&Pl[(rt + l15) * LDP + k0 * 32 + 8 * lq];
        __syncthreads();  // all waves hoisted before Pl is overwritten
        // ---- MFMA + writeback to Pl (f16, bias added)
#pragma unroll
        for (int i = 0; i < 4; i++) {
            f32x4 acc = {0.f, 0.f, 0.f, 0.f};
            const int c0 = (ctb + i) * 16;
#pragma unroll
            for (int k0 = 0; k0 < 4; k0++) {
                f16x8 bf = *(const f16x8*)&Wl[(c0 + l15) * LDP + k0 * 32 + 8 * lq];
                acc = __builtin_amdgcn_mfma_f32_16x16x32_f16(af[k0], bf, acc, 0, 0, 0);
            }
#pragma unroll
            for (int ri = 0; ri < 4; ri++)
                Pl[(rt + lq * 4 + ri) * LDP + c0 + l15] = (f16)(acc[ri] + bv[i]);
        }
        __syncthreads();
        // ---- epilogue: coalesced store + stats (cg = t&15 fixed)
#pragma unroll
        for (int p = 0; p < 2; p++) {
            int u = p * 256 + t;
            int row = u >> 4;
            f16x8 v = *(const f16x8*)&Pl[row * LDP + ca];
            *(f16x8*)&out[(size_t)(tile * 32 + row) * HD + ca] = v;
#pragma unroll
            for (int j = 0; j < 8; j++) {
                float f = (float)v[j];
                s8[j] += f; q8[j] += f * f;
            }
        }
    }

    // ---- stats block reduction (reuse Wl as f32 scratch, 16 KB)
    __syncthreads();
    float* red = (float*)Wl;
#pragma unroll
    for (int j = 0; j < 8; j++) { red[t * 16 + j] = s8[j]; red[t * 16 + 8 + j] = q8[j]; }
    __syncthreads();
    if (t < HD) {
        int g = t >> 3, j = t & 7;
        float ts = 0.f, tq = 0.f;
#pragma unroll
        for (int i = 0; i < 16; i++) {
            ts += red[(i * 16 + g) * 16 + j];
            tq += red[(i * 16 + g) * 16 + 8 + j];
        }
        unsafeAtomicAdd(&gsum[t], ts);
        unsafeAtomicAdd(&gsq[t], tq);
    }
}

// ---------------------------------------------------------------- dense MFMA GEMM (n x 128)@(128 x 128)
// MODE 1: A = relu(f16(in)*tsc+tsh)     (row-major f16 input)
// MODE 2: A = relu((p0[r]-mp)*tsc+tsh)  (scalar f32 per row)
template <int MODE>
__global__ __launch_bounds__(256) void k_gemm(
    const void* __restrict__ in_, const float* __restrict__ W,
    const float* __restrict__ bias,
    const float* __restrict__ tsc, const float* __restrict__ tsh,
    const float* __restrict__ mstat,
    f16* __restrict__ out, float* __restrict__ gsum, float* __restrict__ gsq, int n) {
    __shared__ f16 Wl[HD * LDP];   // 34.8 KB
    __shared__ f16 Al[64 * LDP];   // 17.4 KB
    const int t = threadIdx.x;
    const int lane = t & 63, w = t >> 6;
    const int l15 = lane & 15, lq = lane >> 4;

    for (int p = 0; p < 64; p++) {
        int idx = p * 256 + t;
        Wl[(idx & 127) * LDP + (idx >> 7)] = (f16)W[idx];
    }

    const int ca = (t & 15) * 8;  // staging/epilogue channel base
    float tscv[8], tshv[8];
    *(float4*)&tscv[0] = *(const float4*)&tsc[ca];
    *(float4*)&tscv[4] = *(const float4*)&tsc[ca + 4];
    *(float4*)&tshv[0] = *(const float4*)&tsh[ca];
    *(float4*)&tshv[4] = *(const float4*)&tsh[ca + 4];
    float mp = 0.f;
    if (MODE == 2) mp = mstat[2];
    float bv[8];
#pragma unroll
    for (int ct = 0; ct < 8; ct++) bv[ct] = bias[ct * 16 + l15];

    const int r0 = w * 16;  // wave-exclusive 16 rows
    float s8[8] = {0}, q8[8] = {0};
    const int ntiles = n / 64;
    for (int tile = blockIdx.x; tile < ntiles; tile += gridDim.x) {
        __syncthreads();
        // ---- stage A tile (64 x 128 f16) with fused affine+relu
#pragma unroll
        for (int p = 0; p < 4; p++) {
            const int row = (t >> 4) + p * 16;
            const int grow = tile * 64 + row;
            f16x8 o;
            if (MODE == 1) {
                f16x8 zv = *(const f16x8*)&((const f16*)in_)[(size_t)grow * HD + ca];
#pragma unroll
                for (int j = 0; j < 8; j++)
                    o[j] = (f16)fmaxf((float)zv[j] * tscv[j] + tshv[j], 0.f);
            } else {
                const float pr = ((const float*)in_)[grow] - mp;
#pragma unroll
                for (int j = 0; j < 8; j++)
                    o[j] = (f16)fmaxf(pr * tscv[j] + tshv[j], 0.f);
            }
            *(f16x8*)&Al[row * LDP + ca] = o;
        }
        __syncthreads();
        // ---- hoist A fragments (wave-exclusive rows, no extra sync needed)
        f16x8 af[4];
#pragma unroll
        for (int k0 = 0; k0 < 4; k0++)
            af[k0] = *(const f16x8*)&Al[(r0 + l15) * LDP + k0 * 32 + 8 * lq];
        // ---- 8 col-tiles MFMA; writeback into own rows of Al
#pragma unroll
        for (int ct = 0; ct < 8; ct++) {
            f32x4 acc = {0.f, 0.f, 0.f, 0.f};
#pragma unroll
            for (int k0 = 0; k0 < 4; k0++) {
                f16x8 bf = *(const f16x8*)&Wl[(ct * 16 + l15) * LDP + k0 * 32 + 8 * lq];
                acc = __builtin_amdgcn_mfma_f32_16x16x32_f16(af[k0], bf, acc, 0, 0, 0);
            }
#pragma unroll
            for (int ri = 0; ri < 4; ri++)
                Al[(r0 + lq * 4 + ri) * LDP + ct * 16 + l15] = (f16)(acc[ri] + bv[ct]);
        }
        __syncthreads();
        // ---- epilogue: coalesced store + stats
#pragma unroll
        for (int p = 0; p < 4; p++) {
            int row = (t >> 4) + p * 16;
            f16x8 v = *(const f16x8*)&Al[row * LDP + ca];
            *(f16x8*)&out[(size_t)(tile * 64 + row) * HD + ca] = v;
#pragma unroll
            for (int j = 0; j < 8; j++) {
                float f = (float)v[j];
                s8[j] += f; q8[j] += f * f;
            }
        }
    }

    __syncthreads();
    float* red = (float*)Al;
#pragma unroll
    for (int j = 0; j < 8; j++) { red[t * 16 + j] = s8[j]; red[t * 16 + 8 + j] = q8[j]; }
    __syncthreads();
    if (t < HD) {
        int g = t >> 3, j = t & 7;
        float ts = 0.f, tq = 0.f;
#pragma unroll
        for (int i = 0; i < 16; i++) {
            ts += red[(i * 16 + g) * 16 + j];
            tq += red[(i * 16 + g) * 16 + 8 + j];
        }
        unsafeAtomicAdd(&gsum[t], ts);
        unsafeAtomicAdd(&gsq[t], tq);
    }
}

// mean/var -> affine (sc, sh)
__global__ void k_finalize(const float* __restrict__ gsum, const float* __restrict__ gsq,
                           const float* __restrict__ g, const float* __restrict__ b,
                           float* __restrict__ sc, float* __restrict__ sh, int n) {
    int c = threadIdx.x;
    float m = gsum[c] / n;
    float v = gsq[c] / n - m * m;
    float s = rsqrtf(v + 1e-5f) * g[c];
    sc[c] = s;
    sh[c] = b[c] - m * s;
}

// classifier head (applies final BN affine itself), reads f16 z
__global__ void k_head(const unsigned short* __restrict__ z, const float* __restrict__ sc,
                       const float* __restrict__ sh, const float* __restrict__ fw,
                       const float* __restrict__ fb, float* __restrict__ out, int n) {
    int gid  = blockIdx.x * blockDim.x + threadIdx.x;
    int lane = threadIdx.x & 63;
    int w    = gid >> 6;
    int nw   = (gridDim.x * blockDim.x) >> 6;
    int c    = lane * 2;
    float s0 = sc[c], s1 = sc[c + 1], t0 = sh[c], t1 = sh[c + 1];
    float w00 = fw[c * 2], w01 = fw[c * 2 + 1], w10 = fw[c * 2 + 2], w11 = fw[c * 2 + 3];
    float fb0 = fb[0], fb1 = fb[1];
    for (int r = w; r < n; r += nw) {
        unsigned int u = *(const unsigned int*)&z[(size_t)r * HD + c];
        float zx = h2f((unsigned short)(u & 0xffffu));
        float zy = h2f((unsigned short)(u >> 16));
        float x0 = fmaxf(zx * s0 + t0, 0.f);
        float x1 = fmaxf(zy * s1 + t1, 0.f);
        float l0 = x0 * w00 + x1 * w10;
        float l1 = x0 * w01 + x1 * w11;
#pragma unroll
        for (int o = 32; o > 0; o >>= 1) {
            l0 += __shfl_xor(l0, o, 64);
            l1 += __shfl_xor(l1, o, 64);
        }
        if (lane == 0) {
            l0 += fb0; l1 += fb1;
            float m  = fmaxf(l0, l1);
            float e0 = expf(l0 - m), e1 = expf(l1 - m);
            float inv = 1.f / (e0 + e1);
            *(float2*)&out[(size_t)r * 2] = make_float2(e0 * inv, e1 * inv);
        }
    }
}

extern "C" void kernel_launch(void* const* d_in, const int* in_sizes, int n_in,
                              void* d_out, int out_size, void* d_ws, size_t ws_size,
                              hipStream_t stream) {
    const float* vf    = (const float*)d_in[1];
    const int*   src   = (const int*)d_in[2];
    const int*   dst   = (const int*)d_in[3];
    const float* eps   = (const float*)d_in[4];
    const float* W1_0  = (const float*)d_in[5];
    const float* g1_0  = (const float*)d_in[7];
    const float* bb1_0 = (const float*)d_in[8];
    const float* W2_0  = (const float*)d_in[9];
    const float* b2_0  = (const float*)d_in[10];
    const float* bn0g  = (const float*)d_in[11];
    const float* bn0b  = (const float*)d_in[12];
    const float* W1s   = (const float*)d_in[13];
    const float* b1s   = (const float*)d_in[14];
    const float* g1s   = (const float*)d_in[15];
    const float* bb1s  = (const float*)d_in[16];
    const float* W2s   = (const float*)d_in[17];
    const float* b2s   = (const float*)d_in[18];
    const float* bngs  = (const float*)d_in[19];
    const float* bnbs  = (const float*)d_in[20];
    const float* fw    = (const float*)d_in[21];
    const float* fb    = (const float*)d_in[22];
    float* out = (float*)d_out;

    const int N = in_sizes[1];  // 400000
    const int E = in_sizes[2];  // 6400000

    const size_t needed = (size_t)N * HD * 2 * 2 + (size_t)(N + 8 + 9 * 128 + 512) * 4
                        + (size_t)(2 * N + 1 + E) * 4;
    if (ws_size < needed) {
        float code = (float)(double)(ws_size >> 20);
        k_diag<<<2048, 256, 0, stream>>>(out, out_size, code);
        return;
    }

    f16* H            = (f16*)d_ws;                 // raw z2 (pre-BN), f16
    f16* Z            = H + (size_t)N * HD;         // raw z1 (pre-BN), f16
    float* p0         = (float*)(Z + (size_t)N * HD);
    float* stats      = p0 + N;
    float* gsum       = stats + 8;
    float* gsq        = gsum + HD;
    float* sc1        = gsq + HD;
    float* sh1        = sc1 + HD;
    float* sc2        = sh1 + HD;
    float* sh2        = sc2 + HD;
    float* A0         = sh2 + HD;
    float* Sh0        = A0 + HD;
    int* bsum         = (int*)(Sh0 + HD);
    int* row_ptr      = bsum + 512;
    int* fill         = row_ptr + (N + 1);
    int* src_sorted   = fill + N;

    // -------- CSR build (by dst)
    const int n1 = N + 1;
    const int nsb = (n1 + SCAN_B - 1) / SCAN_B;
    k_zeroi<<<512, 256, 0, stream>>>(row_ptr, n1);
    k_hist<<<4096, 256, 0, stream>>>(dst, row_ptr, E);
    k_scan_block<<<nsb, SCAN_B, 0, stream>>>(row_ptr, n1, bsum);
    k_scan_serial<<<1, 1, 0, stream>>>(bsum, nsb);
    k_scan_add<<<nsb, SCAN_B, 0, stream>>>(row_ptr, n1, bsum);
    k_copyi<<<512, 256, 0, stream>>>(row_ptr, fill, N);
    k_bucket<<<4096, 256, 0, stream>>>(src, dst, fill, src_sorted, E);

    // -------- layer 0 (scalar features, rank-1 inner BN shortcut)
    k_pool0<<<2048, 256, 0, stream>>>(vf, row_ptr, src_sorted, eps, p0, N);
    k_zero<<<1, 256, 0, stream>>>(stats, 8);
    k_p0_stats<<<1024, 256, 0, stream>>>(p0, stats, N);
    k_l0_prep<<<1, 128, 0, stream>>>(stats, W1_0, g1_0, bb1_0, A0, Sh0, N);
    k_zero<<<1, 256, 0, stream>>>(gsum, 2 * HD);
    k_gemm<2><<<2048, 256, 0, stream>>>(p0, W2_0, b2_0, A0, Sh0, stats, H, gsum, gsq, N);
    k_finalize<<<1, 128, 0, stream>>>(gsum, gsq, bn0g, bn0b, sc2, sh2, N);

    // -------- layers 1..3 (H raw; sc2/sh2 applied on the fly in pgemm)
    for (int l = 0; l < 3; l++) {
        k_zero<<<1, 256, 0, stream>>>(gsum, 2 * HD);
        k_pgemm<<<2048, 256, 0, stream>>>(H, row_ptr, src_sorted, eps, l + 1, sc2, sh2,
                                          W1s + (size_t)l * HD * HD, b1s + l * HD,
                                          Z, gsum, gsq, N);
        k_finalize<<<1, 128, 0, stream>>>(gsum, gsq, g1s + l * HD, bb1s + l * HD, sc1, sh1, N);
        k_zero<<<1, 256, 0, stream>>>(gsum, 2 * HD);
        k_gemm<1><<<2048, 256, 0, stream>>>(Z, W2s + (size_t)l * HD * HD, b2s + l * HD,
                                            sc1, sh1, nullptr, H, gsum, gsq, N);
        k_finalize<<<1, 128, 0, stream>>>(gsum, gsq, bngs + l * HD, bnbs + l * HD, sc2, sh2, N);
    }

    // -------- classifier head + softmax
    k_head<<<4096, 256, 0, stream>>>((const unsigned short*)H, sc2, sh2, fw, fb, out, N);
}